// Round 1
// baseline (316.728 us; speedup 1.0000x reference)
//
#include <hip/hip_runtime.h>
#include <hip/hip_bf16.h>
#include <stdint.h>
#include <stddef.h>

using bf16 = __hip_bfloat16;
using bf16x8 = __attribute__((ext_vector_type(8))) short;   // 8 bf16 in 4 VGPRs
using f32x4  = __attribute__((ext_vector_type(4))) float;

#define MFMA16(a, b, c) __builtin_amdgcn_mfma_f32_16x16x32_bf16((a), (b), (c), 0, 0, 0)

#define GLD16(g, l)                                                            \
  __builtin_amdgcn_global_load_lds(                                            \
      (const __attribute__((address_space(1))) void*)(g),                      \
      (__attribute__((address_space(3))) void*)(l), 16, 0, 0)

// ---------------------------------------------------------------- conversions

__global__ void convert_x(const float* __restrict__ x, bf16* __restrict__ out) {
  const int i = blockIdx.x * 256 + threadIdx.x;      // 4096 blocks * 256 * 4 = 4M
  const float4 v = ((const float4*)x)[i];
  __hip_bfloat162* o2 = (__hip_bfloat162*)(out + (size_t)i * 4);
  o2[0] = __float22bfloat162_rn(make_float2(v.x, v.y));
  o2[1] = __float22bfloat162_rn(make_float2(v.z, v.w));
}

// Wt[mat][n][k] = W_mat[k][n]  (B^T layout, bf16)
__global__ void convert_w(const float* __restrict__ W0, const float* __restrict__ W1,
                          const float* __restrict__ W2, const float* __restrict__ W3,
                          bf16* __restrict__ Wt) {
  __shared__ float t[32][33];
  const int bx = blockIdx.x;                  // 4096 = 4 mats * 1024 tiles
  const int mat = bx >> 10;
  const float* W = (mat == 0) ? W0 : (mat == 1) ? W1 : (mat == 2) ? W2 : W3;
  const int rem = bx & 1023;
  const int k0 = (rem >> 5) * 32, n0 = (rem & 31) * 32;
  const int c = threadIdx.x & 31, r0 = (threadIdx.x >> 5) * 4;
#pragma unroll
  for (int i = 0; i < 4; ++i) {
    const int r = r0 + i;
    t[r][c] = W[(size_t)(k0 + r) * 1024 + n0 + c];
  }
  __syncthreads();
  bf16* dst = Wt + (size_t)mat * 1024 * 1024;
#pragma unroll
  for (int i = 0; i < 4; ++i) {
    const int rn = r0 + i;   // n index
    dst[(size_t)(n0 + rn) * 1024 + k0 + c] = __float2bfloat16(t[c][rn]);
  }
}

__global__ void concat_bias(const float* __restrict__ bq, const float* __restrict__ bk,
                            const float* __restrict__ bv, const float* __restrict__ bo,
                            float* __restrict__ dst) {
  const int i = blockIdx.x * 256 + threadIdx.x;   // 16 blocks -> 4096
  const float* src = (i < 1024) ? bq : (i < 2048) ? bk : (i < 3072) ? bv : bo;
  dst[i] = src[i & 1023];
}

// ---------------------------------------------------------------- GEMM (A[M,K] * Bt[N,K]^T + bias)
// MODE 0: QKV fused (N=3072): scatter to Q[bh,t,d], K[bh,t,d], Vt[bh,d,t] (bf16)
// MODE 1: output proj (N=1024): fp32 out[row*1024+col]

template <int MODE>
__global__ __launch_bounds__(256)
void gemm_bt(const bf16* __restrict__ A, const bf16* __restrict__ Bt,
             const float* __restrict__ bias,
             bf16* __restrict__ Qb, bf16* __restrict__ Kb, bf16* __restrict__ Vt,
             float* __restrict__ Of, int K) {
  __shared__ bf16 As[128 * 32];
  __shared__ bf16 Bs[128 * 32];
  const int tid = threadIdx.x;
  const int lane = tid & 63, w = tid >> 6;
  const int wr = w >> 1, wc = w & 1;
  const int lrow = lane & 15, lgk = lane >> 4;
  const int bm = blockIdx.y * 128, bn = blockIdx.x * 128;
  f32x4 acc[4][4] = {};
  const bf16* Ab = A + (size_t)bm * K;
  const bf16* Bb = Bt + (size_t)bn * K;
  const int e0 = tid, e1 = 256 + tid;

  for (int k0 = 0; k0 < K; k0 += 32) {
    GLD16(Ab + (size_t)(e0 >> 2) * K + k0 + (e0 & 3) * 8, As + e0 * 8);
    GLD16(Ab + (size_t)(e1 >> 2) * K + k0 + (e1 & 3) * 8, As + e1 * 8);
    GLD16(Bb + (size_t)(e0 >> 2) * K + k0 + (e0 & 3) * 8, Bs + e0 * 8);
    GLD16(Bb + (size_t)(e1 >> 2) * K + k0 + (e1 & 3) * 8, Bs + e1 * 8);
    asm volatile("s_waitcnt vmcnt(0)" ::: "memory");
    __syncthreads();
    bf16x8 af[4], bfr[4];
#pragma unroll
    for (int m = 0; m < 4; ++m)
      af[m] = *(const bf16x8*)(As + (wr * 64 + m * 16 + lrow) * 32 + lgk * 8);
#pragma unroll
    for (int n = 0; n < 4; ++n)
      bfr[n] = *(const bf16x8*)(Bs + (wc * 64 + n * 16 + lrow) * 32 + lgk * 8);
#pragma unroll
    for (int m = 0; m < 4; ++m)
#pragma unroll
      for (int n = 0; n < 4; ++n)
        acc[m][n] = MFMA16(af[m], bfr[n], acc[m][n]);
    __syncthreads();
  }

#pragma unroll
  for (int m = 0; m < 4; ++m) {
#pragma unroll
    for (int n = 0; n < 4; ++n) {
      const int col = bn + wc * 64 + n * 16 + lrow;
      const float bv_ = bias[col];
      const int row0 = bm + wr * 64 + m * 16 + lgk * 4;
      if (MODE == 0) {
        const int which = col >> 10;
        const int hd = col & 1023;
        const int h = hd >> 6, d = hd & 63;
#pragma unroll
        for (int j = 0; j < 4; ++j) {
          const int row = row0 + j;
          const int b = row >> 11, t = row & 2047;
          const int bh = b * 16 + h;
          const float v = acc[m][n][j] + bv_;
          if (which == 0)
            Qb[((size_t)bh * 2048 + t) * 64 + d] = __float2bfloat16(v);
          else if (which == 1)
            Kb[((size_t)bh * 2048 + t) * 64 + d] = __float2bfloat16(v);
          else
            Vt[((size_t)bh * 64 + d) * 2048 + t] = __float2bfloat16(v);
        }
      } else {
#pragma unroll
        for (int j = 0; j < 4; ++j) {
          const int row = row0 + j;
          Of[(size_t)row * 1024 + col] = acc[m][n][j] + bv_;
        }
      }
    }
  }
}

// ---------------------------------------------------------------- flash attention
// Q[bh, t, d], K[bh, t, d], Vt[bh, d, t]  (bh = b*16+h), ctx[b*2048+t, h*64+d] bf16
__global__ __launch_bounds__(256)
void attn_kernel(const bf16* __restrict__ Q, const bf16* __restrict__ Kb,
                 const bf16* __restrict__ Vt, bf16* __restrict__ ctx) {
  __shared__ bf16 Pl[4][16][72];   // per-wave, +8 pad to break bank conflicts
  const int tid = threadIdx.x, lane = tid & 63, w = tid >> 6;
  const int lrow = lane & 15, lgk = lane >> 4;
  const int bh = blockIdx.y;
  const int q0 = blockIdx.x * 64 + w * 16;

  const bf16* Qp = Q + ((size_t)bh * 2048 + q0 + lrow) * 64 + lgk * 8;
  const bf16x8 qf0 = *(const bf16x8*)Qp;
  const bf16x8 qf1 = *(const bf16x8*)(Qp + 32);
  const bf16* Kbh = Kb + (size_t)bh * 2048 * 64;
  const bf16* Vbh = Vt + (size_t)bh * 64 * 2048;

  f32x4 o[4] = {};
  float mrow[4] = {-1e30f, -1e30f, -1e30f, -1e30f};
  float lsum[4] = {0.f, 0.f, 0.f, 0.f};

  for (int kv = 0; kv < 2048; kv += 64) {
    f32x4 s[4] = {};
#pragma unroll
    for (int f = 0; f < 4; ++f) {
      const bf16* Kp = Kbh + (size_t)(kv + f * 16 + lrow) * 64 + lgk * 8;
      const bf16x8 kf0 = *(const bf16x8*)Kp;
      const bf16x8 kf1 = *(const bf16x8*)(Kp + 32);
      s[f] = MFMA16(qf0, kf0, s[f]);
      s[f] = MFMA16(qf1, kf1, s[f]);
    }
    float sc[4][4];   // [f][j] scaled scores
#pragma unroll
    for (int f = 0; f < 4; ++f)
#pragma unroll
      for (int j = 0; j < 4; ++j) sc[f][j] = s[f][j] * 0.125f;

    float corr[4];
#pragma unroll
    for (int j = 0; j < 4; ++j) {
      float mx = fmaxf(fmaxf(sc[0][j], sc[1][j]), fmaxf(sc[2][j], sc[3][j]));
      mx = fmaxf(mx, __shfl_xor(mx, 1, 64));
      mx = fmaxf(mx, __shfl_xor(mx, 2, 64));
      mx = fmaxf(mx, __shfl_xor(mx, 4, 64));
      mx = fmaxf(mx, __shfl_xor(mx, 8, 64));
      const float nm = fmaxf(mrow[j], mx);
      corr[j] = __expf(mrow[j] - nm);
      mrow[j] = nm;
      float rs = 0.f;
#pragma unroll
      for (int f = 0; f < 4; ++f) {
        const float p = __expf(sc[f][j] - nm);
        sc[f][j] = p;
        rs += p;
      }
      rs += __shfl_xor(rs, 1, 64);
      rs += __shfl_xor(rs, 2, 64);
      rs += __shfl_xor(rs, 4, 64);
      rs += __shfl_xor(rs, 8, 64);
      lsum[j] = lsum[j] * corr[j] + rs;
    }
#pragma unroll
    for (int dt = 0; dt < 4; ++dt)
#pragma unroll
      for (int j = 0; j < 4; ++j) o[dt][j] *= corr[j];

    // P -> LDS (per-wave region; cross-lane redistribute for PV A-fragments)
#pragma unroll
    for (int j = 0; j < 4; ++j)
#pragma unroll
      for (int f = 0; f < 4; ++f)
        Pl[w][lgk * 4 + j][lrow + 16 * f] = __float2bfloat16(sc[f][j]);
    asm volatile("s_waitcnt lgkmcnt(0)" ::: "memory");
    __builtin_amdgcn_sched_barrier(0);

#pragma unroll
    for (int ks = 0; ks < 2; ++ks) {
      const bf16x8 pf = *(const bf16x8*)(&Pl[w][lrow][ks * 32 + lgk * 8]);
#pragma unroll
      for (int dt = 0; dt < 4; ++dt) {
        const bf16* Vp = Vbh + (size_t)(dt * 16 + lrow) * 2048 + kv + ks * 32 + lgk * 8;
        const bf16x8 vf = *(const bf16x8*)Vp;
        o[dt] = MFMA16(pf, vf, o[dt]);
      }
    }
  }

  float inv[4];
#pragma unroll
  for (int j = 0; j < 4; ++j) inv[j] = 1.f / lsum[j];
  const int b = bh >> 4, h = bh & 15;
#pragma unroll
  for (int dt = 0; dt < 4; ++dt)
#pragma unroll
    for (int j = 0; j < 4; ++j) {
      const size_t tok = (size_t)b * 2048 + q0 + lgk * 4 + j;
      ctx[tok * 1024 + h * 64 + dt * 16 + lrow] = __float2bfloat16(o[dt][j] * inv[j]);
    }
}

// ---------------------------------------------------------------- launch

extern "C" void kernel_launch(void* const* d_in, const int* in_sizes, int n_in,
                              void* d_out, int out_size, void* d_ws, size_t ws_size,
                              hipStream_t stream) {
  const float* x  = (const float*)d_in[0];
  const float* Wq = (const float*)d_in[1];
  const float* bq = (const float*)d_in[2];
  const float* Wk = (const float*)d_in[3];
  const float* bk = (const float*)d_in[4];
  const float* Wv = (const float*)d_in[5];
  const float* bv = (const float*)d_in[6];
  const float* Wo = (const float*)d_in[7];
  const float* bo = (const float*)d_in[8];
  float* out = (float*)d_out;

  char* ws = (char*)d_ws;
  bf16* xb  = (bf16*)(ws);                       // 8 MiB  (4096x1024)
  bf16* Wt  = (bf16*)(ws + ((size_t)8 << 20));   // 8 MiB  (4096x1024: Wq^T|Wk^T|Wv^T|Wo^T)
  bf16* Qb  = (bf16*)(ws + ((size_t)16 << 20));  // 8 MiB  [32][2048][64]
  bf16* Kb  = (bf16*)(ws + ((size_t)24 << 20));  // 8 MiB  [32][2048][64]
  bf16* Vt  = (bf16*)(ws + ((size_t)32 << 20));  // 8 MiB  [32][64][2048]
  bf16* ctx = (bf16*)(ws + ((size_t)40 << 20));  // 8 MiB  [4096][1024]
  float* ba = (float*)(ws + ((size_t)48 << 20)); // 16 KiB

  convert_x<<<dim3(4096), dim3(256), 0, stream>>>(x, xb);
  convert_w<<<dim3(4096), dim3(256), 0, stream>>>(Wq, Wk, Wv, Wo, Wt);
  concat_bias<<<dim3(16), dim3(256), 0, stream>>>(bq, bk, bv, bo, ba);

  // QKV fused GEMM: [4096,1024] x [1024,3072]
  gemm_bt<0><<<dim3(24, 32), dim3(256), 0, stream>>>(xb, Wt, ba, Qb, Kb, Vt, nullptr, 1024);

  // flash attention: 32 q-tiles x 32 (b,h)
  attn_kernel<<<dim3(32, 32), dim3(256), 0, stream>>>(Qb, Kb, Vt, ctx);

  // output projection: [4096,1024] x [1024,1024] -> fp32 d_out
  gemm_bt<1><<<dim3(8, 32), dim3(256), 0, stream>>>(
      ctx, Wt + (size_t)3072 * 1024, ba + 3072, nullptr, nullptr, nullptr, out, 1024);
}

// Round 2
// 207.419 us; speedup vs baseline: 1.5270x; 1.5270x over previous
//
#include <hip/hip_runtime.h>
#include <hip/hip_bf16.h>
#include <stdint.h>
#include <stddef.h>

using bf16 = __hip_bfloat16;
using bf16x8 = __attribute__((ext_vector_type(8))) short;   // 8 bf16 in 4 VGPRs
using f32x4  = __attribute__((ext_vector_type(4))) float;
using f32x16 = __attribute__((ext_vector_type(16))) float;
typedef unsigned int u32x2 __attribute__((ext_vector_type(2)));
typedef unsigned int u32x4 __attribute__((ext_vector_type(4)));

#define MFMA16(a, b, c) __builtin_amdgcn_mfma_f32_16x16x32_bf16((a), (b), (c), 0, 0, 0)
#define MFMA32(a, b, c) __builtin_amdgcn_mfma_f32_32x32x16_bf16((a), (b), (c), 0, 0, 0)

#define GLD16(g, l)                                                            \
  __builtin_amdgcn_global_load_lds(                                            \
      (const __attribute__((address_space(1))) void*)(g),                      \
      (__attribute__((address_space(3))) void*)(l), 16, 0, 0)

__device__ __forceinline__ float exp2_fast(float x) {
#if __has_builtin(__builtin_amdgcn_exp2f)
  return __builtin_amdgcn_exp2f(x);
#else
  return __expf(x * 0.69314718056f);
#endif
}

__device__ __forceinline__ unsigned int cvtpk_bf16(float lo, float hi) {
  unsigned int r;
  asm("v_cvt_pk_bf16_f32 %0, %1, %2" : "=v"(r) : "v"(lo), "v"(hi));
  return r;
}

// (a,b) -> a' = {a.lo32lanes, b.lo32lanes}; b' = {a.hi32lanes, b.hi32lanes}
__device__ __forceinline__ void permswap(unsigned int& a, unsigned int& b, int hi) {
#if __has_builtin(__builtin_amdgcn_permlane32_swap)
  u32x2 r = __builtin_amdgcn_permlane32_swap(a, b, false, false);
  a = r.x;
  b = r.y;
#else
  unsigned int sa = __shfl_xor((unsigned int)a, 32, 64);
  unsigned int sb = __shfl_xor((unsigned int)b, 32, 64);
  unsigned int an = hi ? sb : a;
  unsigned int bn = hi ? b : sa;
  a = an; b = bn;
#endif
}

// ---------------------------------------------------------------- conversions

__global__ void convert_x(const float* __restrict__ x, bf16* __restrict__ out) {
  const int i = blockIdx.x * 256 + threadIdx.x;
  const float4 v = ((const float4*)x)[i];
  __hip_bfloat162* o2 = (__hip_bfloat162*)(out + (size_t)i * 4);
  o2[0] = __float22bfloat162_rn(make_float2(v.x, v.y));
  o2[1] = __float22bfloat162_rn(make_float2(v.z, v.w));
}

__global__ void convert_w(const float* __restrict__ W0, const float* __restrict__ W1,
                          const float* __restrict__ W2, const float* __restrict__ W3,
                          bf16* __restrict__ Wt) {
  __shared__ float t[32][33];
  const int bx = blockIdx.x;
  const int mat = bx >> 10;
  const float* W = (mat == 0) ? W0 : (mat == 1) ? W1 : (mat == 2) ? W2 : W3;
  const int rem = bx & 1023;
  const int k0 = (rem >> 5) * 32, n0 = (rem & 31) * 32;
  const int c = threadIdx.x & 31, r0 = (threadIdx.x >> 5) * 4;
#pragma unroll
  for (int i = 0; i < 4; ++i) {
    const int r = r0 + i;
    t[r][c] = W[(size_t)(k0 + r) * 1024 + n0 + c];
  }
  __syncthreads();
  bf16* dst = Wt + (size_t)mat * 1024 * 1024;
#pragma unroll
  for (int i = 0; i < 4; ++i) {
    const int rn = r0 + i;
    dst[(size_t)(n0 + rn) * 1024 + k0 + c] = __float2bfloat16(t[c][rn]);
  }
}

__global__ void concat_bias(const float* __restrict__ bq, const float* __restrict__ bk,
                            const float* __restrict__ bv, const float* __restrict__ bo,
                            float* __restrict__ dst) {
  const int i = blockIdx.x * 256 + threadIdx.x;
  const float* src = (i < 1024) ? bq : (i < 2048) ? bk : (i < 3072) ? bv : bo;
  dst[i] = src[i & 1023];
}

// ---------------------------------------------------------------- GEMM (A[M,K] * Bt[N,K]^T + bias)

template <int MODE>
__global__ __launch_bounds__(256)
void gemm_bt(const bf16* __restrict__ A, const bf16* __restrict__ Bt,
             const float* __restrict__ bias,
             bf16* __restrict__ Qb, bf16* __restrict__ Kb, bf16* __restrict__ Vt,
             float* __restrict__ Of, int K) {
  __shared__ bf16 As[128 * 32];
  __shared__ bf16 Bs[128 * 32];
  const int tid = threadIdx.x;
  const int lane = tid & 63, w = tid >> 6;
  const int wr = w >> 1, wc = w & 1;
  const int lrow = lane & 15, lgk = lane >> 4;
  const int bm = blockIdx.y * 128, bn = blockIdx.x * 128;
  f32x4 acc[4][4] = {};
  const bf16* Ab = A + (size_t)bm * K;
  const bf16* Bb = Bt + (size_t)bn * K;
  const int e0 = tid, e1 = 256 + tid;

  for (int k0 = 0; k0 < K; k0 += 32) {
    GLD16(Ab + (size_t)(e0 >> 2) * K + k0 + (e0 & 3) * 8, As + e0 * 8);
    GLD16(Ab + (size_t)(e1 >> 2) * K + k0 + (e1 & 3) * 8, As + e1 * 8);
    GLD16(Bb + (size_t)(e0 >> 2) * K + k0 + (e0 & 3) * 8, Bs + e0 * 8);
    GLD16(Bb + (size_t)(e1 >> 2) * K + k0 + (e1 & 3) * 8, Bs + e1 * 8);
    asm volatile("s_waitcnt vmcnt(0)" ::: "memory");
    __syncthreads();
    bf16x8 af[4], bfr[4];
#pragma unroll
    for (int m = 0; m < 4; ++m)
      af[m] = *(const bf16x8*)(As + (wr * 64 + m * 16 + lrow) * 32 + lgk * 8);
#pragma unroll
    for (int n = 0; n < 4; ++n)
      bfr[n] = *(const bf16x8*)(Bs + (wc * 64 + n * 16 + lrow) * 32 + lgk * 8);
#pragma unroll
    for (int m = 0; m < 4; ++m)
#pragma unroll
      for (int n = 0; n < 4; ++n)
        acc[m][n] = MFMA16(af[m], bfr[n], acc[m][n]);
    __syncthreads();
  }

#pragma unroll
  for (int m = 0; m < 4; ++m) {
#pragma unroll
    for (int n = 0; n < 4; ++n) {
      const int col = bn + wc * 64 + n * 16 + lrow;
      const float bv_ = bias[col];
      const int row0 = bm + wr * 64 + m * 16 + lgk * 4;
      if (MODE == 0) {
        const int which = col >> 10;
        const int hd = col & 1023;
        const int h = hd >> 6, d = hd & 63;
#pragma unroll
        for (int j = 0; j < 4; ++j) {
          const int row = row0 + j;
          const int b = row >> 11, t = row & 2047;
          const int bh = b * 16 + h;
          const float v = acc[m][n][j] + bv_;
          if (which == 0)
            Qb[((size_t)bh * 2048 + t) * 64 + d] = __float2bfloat16(v);
          else if (which == 1)
            Kb[((size_t)bh * 2048 + t) * 64 + d] = __float2bfloat16(v);
          else
            Vt[((size_t)bh * 64 + d) * 2048 + t] = __float2bfloat16(v);
        }
      } else {
#pragma unroll
        for (int j = 0; j < 4; ++j) {
          const int row = row0 + j;
          Of[(size_t)row * 1024 + col] = acc[m][n][j] + bv_;
        }
      }
    }
  }
}

// ---------------------------------------------------------------- flash attention (swapped QK^T, in-register softmax)
// Q[bh,t,d], K[bh,t,d], Vt[bh,d,t]; ctx[b*2048+t, h*64+d] bf16
// Wave owns 32 q-rows. S^T = mfma32(K, Q): lane col = q (lane&31), kv rows in regs.
// O^T = mfma32(V^T, P^T): lane col = q, d rows in regs.
__global__ __launch_bounds__(256)
void attn_kernel(const bf16* __restrict__ Q, const bf16* __restrict__ Kb,
                 const bf16* __restrict__ Vt, bf16* __restrict__ ctx) {
  const int tid = threadIdx.x, lane = tid & 63, w = tid >> 6;
  const int lo5 = lane & 31, hi = lane >> 5;
  const int bh = blockIdx.y;
  const int q0 = blockIdx.x * 128 + w * 32;

  const bf16* Qbh = Q + (size_t)bh * 2048 * 64;
  const bf16* Kbh = Kb + (size_t)bh * 2048 * 64;
  const bf16* Vbh = Vt + (size_t)bh * 64 * 2048;

  // Q B-fragments: col = lo5 (q), k = f*16 + hi*8 + e
  bf16x8 qf[4];
#pragma unroll
  for (int f = 0; f < 4; ++f)
    qf[f] = *(const bf16x8*)(Qbh + (size_t)(q0 + lo5) * 64 + f * 16 + hi * 8);

  f32x16 o0 = {}, o1 = {};
  float m2 = -1e30f;     // running max in exp2 domain
  float lsum = 0.f;      // per-half partial denominator
  const float SC = 0.125f * 1.44269504f;   // 1/sqrt(64) * log2(e)

  bf16x8 kb0[8], kb1[8];   // K A-fragments double buffer: [kt*4+f]
#define LOADK(kvbase, dst)                                                     \
  {                                                                            \
    _Pragma("unroll") for (int kt = 0; kt < 2; ++kt)                           \
        _Pragma("unroll") for (int f = 0; f < 4; ++f)                          \
            dst[kt * 4 + f] = *(const bf16x8*)(Kbh +                           \
                (size_t)((kvbase) + kt * 32 + lo5) * 64 + f * 16 + hi * 8);    \
  }

  LOADK(0, kb0);

  auto step = [&](int kv, bf16x8* kcur, bf16x8* knext) {
    // V A-fragments: row = lo5 (d), k = kv + ks*16 + hi*8 + e
    bf16x8 vf[8];   // [dt*4+ks]
#pragma unroll
    for (int dt = 0; dt < 2; ++dt)
#pragma unroll
      for (int ks = 0; ks < 4; ++ks)
        vf[dt * 4 + ks] = *(const bf16x8*)(Vbh + (size_t)(dt * 32 + lo5) * 2048 +
                                           kv + ks * 16 + hi * 8);
    // prefetch next K tile
    const int kvn = (kv + 64 < 2048) ? kv + 64 : 0;
    LOADK(kvn, knext);

    // QK^T
    f32x16 s0 = {}, s1 = {};
#pragma unroll
    for (int f = 0; f < 4; ++f) s0 = MFMA32(kcur[f], qf[f], s0);
#pragma unroll
    for (int f = 0; f < 4; ++f) s1 = MFMA32(kcur[4 + f], qf[f], s1);

    // softmax (in-register; lane owns one q-column, 32 kv values)
    float p[32];
#pragma unroll
    for (int j = 0; j < 16; ++j) { p[j] = s0[j] * SC; p[16 + j] = s1[j] * SC; }
    float pm = p[0];
#pragma unroll
    for (int j = 1; j < 32; ++j) pm = fmaxf(pm, p[j]);
    if (!__all(pm <= m2 + 11.5416f)) {   // defer-max (THR = 8 nats in log2)
      const float mx = fmaxf(pm, __shfl_xor(pm, 32, 64));
      const float mn = fmaxf(m2, mx);
      const float corr = exp2_fast(m2 - mn);
      m2 = mn;
      lsum *= corr;
#pragma unroll
      for (int j = 0; j < 16; ++j) { o0[j] *= corr; o1[j] *= corr; }
    }
    float rs = 0.f;
#pragma unroll
    for (int j = 0; j < 32; ++j) {
      p[j] = exp2_fast(p[j] - m2);
      rs += p[j];
    }
    lsum += rs;

    // build P^T B-fragments: pa[ks] covers kv-local [16ks, 16ks+16)
    bf16x8 pa[4];
#pragma unroll
    for (int ks = 0; ks < 4; ++ks) {
      const int b0 = ks * 8;
      unsigned int a0 = cvtpk_bf16(p[b0 + 0], p[b0 + 1]);
      unsigned int c0 = cvtpk_bf16(p[b0 + 4], p[b0 + 5]);
      unsigned int a1 = cvtpk_bf16(p[b0 + 2], p[b0 + 3]);
      unsigned int c1 = cvtpk_bf16(p[b0 + 6], p[b0 + 7]);
      permswap(a0, c0, hi);   // -> (w0, w2)
      permswap(a1, c1, hi);   // -> (w1, w3)
      u32x4 t;
      t.x = a0; t.y = a1; t.z = c0; t.w = c1;
      pa[ks] = __builtin_bit_cast(bf16x8, t);
    }

    // PV: O^T += V^T * P^T
#pragma unroll
    for (int ks = 0; ks < 4; ++ks) {
      o0 = MFMA32(vf[ks], pa[ks], o0);
      o1 = MFMA32(vf[4 + ks], pa[ks], o1);
    }
  };

  for (int kv = 0; kv < 2048; kv += 128) {
    step(kv, kb0, kb1);
    step(kv + 64, kb1, kb0);
  }

  lsum += __shfl_xor(lsum, 32, 64);
  const float inv = 1.f / lsum;
  const int b = bh >> 4, h = bh & 15;
  bf16* crow = ctx + (size_t)(b * 2048 + q0 + lo5) * 1024 + h * 64;
#pragma unroll
  for (int g = 0; g < 4; ++g) {
    // regs 4g..4g+3 -> d = 8g + 4hi + 0..3 (consecutive)
    uint2 pk0, pk1;
    pk0.x = cvtpk_bf16(o0[4 * g + 0] * inv, o0[4 * g + 1] * inv);
    pk0.y = cvtpk_bf16(o0[4 * g + 2] * inv, o0[4 * g + 3] * inv);
    pk1.x = cvtpk_bf16(o1[4 * g + 0] * inv, o1[4 * g + 1] * inv);
    pk1.y = cvtpk_bf16(o1[4 * g + 2] * inv, o1[4 * g + 3] * inv);
    *(uint2*)(crow + 8 * g + 4 * hi) = pk0;
    *(uint2*)(crow + 32 + 8 * g + 4 * hi) = pk1;
  }
}

// ---------------------------------------------------------------- launch

extern "C" void kernel_launch(void* const* d_in, const int* in_sizes, int n_in,
                              void* d_out, int out_size, void* d_ws, size_t ws_size,
                              hipStream_t stream) {
  const float* x  = (const float*)d_in[0];
  const float* Wq = (const float*)d_in[1];
  const float* bq = (const float*)d_in[2];
  const float* Wk = (const float*)d_in[3];
  const float* bk = (const float*)d_in[4];
  const float* Wv = (const float*)d_in[5];
  const float* bv = (const float*)d_in[6];
  const float* Wo = (const float*)d_in[7];
  const float* bo = (const float*)d_in[8];
  float* out = (float*)d_out;

  char* ws = (char*)d_ws;
  bf16* xb  = (bf16*)(ws);
  bf16* Wt  = (bf16*)(ws + ((size_t)8 << 20));
  bf16* Qb  = (bf16*)(ws + ((size_t)16 << 20));
  bf16* Kb  = (bf16*)(ws + ((size_t)24 << 20));
  bf16* Vt  = (bf16*)(ws + ((size_t)32 << 20));
  bf16* ctx = (bf16*)(ws + ((size_t)40 << 20));
  float* ba = (float*)(ws + ((size_t)48 << 20));

  convert_x<<<dim3(4096), dim3(256), 0, stream>>>(x, xb);
  convert_w<<<dim3(4096), dim3(256), 0, stream>>>(Wq, Wk, Wv, Wo, Wt);
  concat_bias<<<dim3(16), dim3(256), 0, stream>>>(bq, bk, bv, bo, ba);

  gemm_bt<0><<<dim3(24, 32), dim3(256), 0, stream>>>(xb, Wt, ba, Qb, Kb, Vt, nullptr, 1024);

  attn_kernel<<<dim3(16, 32), dim3(256), 0, stream>>>(Qb, Kb, Vt, ctx);

  gemm_bt<1><<<dim3(8, 32), dim3(256), 0, stream>>>(
      ctx, Wt + (size_t)3072 * 1024, ba + 3072, nullptr, nullptr, nullptr, out, 1024);
}

// Round 3
// 144.158 us; speedup vs baseline: 2.1971x; 1.4388x over previous
//
#include <hip/hip_runtime.h>
#include <hip/hip_bf16.h>
#include <stdint.h>
#include <stddef.h>

using bf16 = __hip_bfloat16;
using bf16x8 = __attribute__((ext_vector_type(8))) short;   // 8 bf16 in 4 VGPRs
using f32x4  = __attribute__((ext_vector_type(4))) float;
using f32x16 = __attribute__((ext_vector_type(16))) float;
typedef unsigned int u32x2 __attribute__((ext_vector_type(2)));
typedef unsigned int u32x4 __attribute__((ext_vector_type(4)));

#define MFMA16(a, b, c) __builtin_amdgcn_mfma_f32_16x16x32_bf16((a), (b), (c), 0, 0, 0)
#define MFMA32(a, b, c) __builtin_amdgcn_mfma_f32_32x32x16_bf16((a), (b), (c), 0, 0, 0)

#define GLD16(g, l)                                                            \
  __builtin_amdgcn_global_load_lds(                                            \
      (const __attribute__((address_space(1))) void*)(g),                      \
      (__attribute__((address_space(3))) void*)(l), 16, 0, 0)

__device__ __forceinline__ float exp2_fast(float x) {
#if __has_builtin(__builtin_amdgcn_exp2f)
  return __builtin_amdgcn_exp2f(x);
#else
  return __expf(x * 0.69314718056f);
#endif
}

__device__ __forceinline__ unsigned int cvtpk_bf16(float lo, float hi) {
  unsigned int r;
  asm("v_cvt_pk_bf16_f32 %0, %1, %2" : "=v"(r) : "v"(lo), "v"(hi));
  return r;
}

__device__ __forceinline__ void permswap(unsigned int& a, unsigned int& b, int hi) {
#if __has_builtin(__builtin_amdgcn_permlane32_swap)
  u32x2 r = __builtin_amdgcn_permlane32_swap(a, b, false, false);
  a = r.x;
  b = r.y;
#else
  unsigned int sa = __shfl_xor((unsigned int)a, 32, 64);
  unsigned int sb = __shfl_xor((unsigned int)b, 32, 64);
  unsigned int an = hi ? sb : a;
  unsigned int bn = hi ? b : sa;
  a = an; b = bn;
#endif
}

// ---------------------------------------------------------------- conversions

__global__ void convert_x(const float* __restrict__ x, bf16* __restrict__ out) {
  const int i = blockIdx.x * 256 + threadIdx.x;
  const float4 v = ((const float4*)x)[i];
  __hip_bfloat162* o2 = (__hip_bfloat162*)(out + (size_t)i * 4);
  o2[0] = __float22bfloat162_rn(make_float2(v.x, v.y));
  o2[1] = __float22bfloat162_rn(make_float2(v.z, v.w));
}

__global__ void convert_w(const float* __restrict__ W0, const float* __restrict__ W1,
                          const float* __restrict__ W2, const float* __restrict__ W3,
                          bf16* __restrict__ Wt) {
  __shared__ float t[32][33];
  const int bx = blockIdx.x;
  const int mat = bx >> 10;
  const float* W = (mat == 0) ? W0 : (mat == 1) ? W1 : (mat == 2) ? W2 : W3;
  const int rem = bx & 1023;
  const int k0 = (rem >> 5) * 32, n0 = (rem & 31) * 32;
  const int c = threadIdx.x & 31, r0 = (threadIdx.x >> 5) * 4;
#pragma unroll
  for (int i = 0; i < 4; ++i) {
    const int r = r0 + i;
    t[r][c] = W[(size_t)(k0 + r) * 1024 + n0 + c];
  }
  __syncthreads();
  bf16* dst = Wt + (size_t)mat * 1024 * 1024;
#pragma unroll
  for (int i = 0; i < 4; ++i) {
    const int rn = r0 + i;
    dst[(size_t)(n0 + rn) * 1024 + k0 + c] = __float2bfloat16(t[c][rn]);
  }
}

__global__ void concat_bias(const float* __restrict__ bq, const float* __restrict__ bk,
                            const float* __restrict__ bv, const float* __restrict__ bo,
                            float* __restrict__ dst) {
  const int i = blockIdx.x * 256 + threadIdx.x;
  const float* src = (i < 1024) ? bq : (i < 2048) ? bk : (i < 3072) ? bv : bo;
  dst[i] = src[i & 1023];
}

// ---------------------------------------------------------------- GEMM (A[M,K] * Bt[N,K]^T + bias)

template <int MODE>
__global__ __launch_bounds__(256)
void gemm_bt(const bf16* __restrict__ A, const bf16* __restrict__ Bt,
             const float* __restrict__ bias,
             bf16* __restrict__ Qb, bf16* __restrict__ Kb, bf16* __restrict__ Vt,
             float* __restrict__ Of, int K) {
  __shared__ bf16 As[128 * 32];
  __shared__ bf16 Bs[128 * 32];
  const int tid = threadIdx.x;
  const int lane = tid & 63, w = tid >> 6;
  const int wr = w >> 1, wc = w & 1;
  const int lrow = lane & 15, lgk = lane >> 4;
  const int bm = blockIdx.y * 128, bn = blockIdx.x * 128;
  f32x4 acc[4][4] = {};
  const bf16* Ab = A + (size_t)bm * K;
  const bf16* Bb = Bt + (size_t)bn * K;
  const int e0 = tid, e1 = 256 + tid;

  for (int k0 = 0; k0 < K; k0 += 32) {
    GLD16(Ab + (size_t)(e0 >> 2) * K + k0 + (e0 & 3) * 8, As + e0 * 8);
    GLD16(Ab + (size_t)(e1 >> 2) * K + k0 + (e1 & 3) * 8, As + e1 * 8);
    GLD16(Bb + (size_t)(e0 >> 2) * K + k0 + (e0 & 3) * 8, Bs + e0 * 8);
    GLD16(Bb + (size_t)(e1 >> 2) * K + k0 + (e1 & 3) * 8, Bs + e1 * 8);
    asm volatile("s_waitcnt vmcnt(0)" ::: "memory");
    __syncthreads();
    bf16x8 af[4], bfr[4];
#pragma unroll
    for (int m = 0; m < 4; ++m)
      af[m] = *(const bf16x8*)(As + (wr * 64 + m * 16 + lrow) * 32 + lgk * 8);
#pragma unroll
    for (int n = 0; n < 4; ++n)
      bfr[n] = *(const bf16x8*)(Bs + (wc * 64 + n * 16 + lrow) * 32 + lgk * 8);
#pragma unroll
    for (int m = 0; m < 4; ++m)
#pragma unroll
      for (int n = 0; n < 4; ++n)
        acc[m][n] = MFMA16(af[m], bfr[n], acc[m][n]);
    __syncthreads();
  }

#pragma unroll
  for (int m = 0; m < 4; ++m) {
#pragma unroll
    for (int n = 0; n < 4; ++n) {
      const int col = bn + wc * 64 + n * 16 + lrow;
      const float bv_ = bias[col];
      const int row0 = bm + wr * 64 + m * 16 + lgk * 4;
      if (MODE == 0) {
        const int which = col >> 10;
        const int hd = col & 1023;
        const int h = hd >> 6, d = hd & 63;
#pragma unroll
        for (int j = 0; j < 4; ++j) {
          const int row = row0 + j;
          const int b = row >> 11, t = row & 2047;
          const int bh = b * 16 + h;
          const float v = acc[m][n][j] + bv_;
          if (which == 0)
            Qb[((size_t)bh * 2048 + t) * 64 + d] =
                __float2bfloat16(v * 0.18033688f);   // fold 1/sqrt(64)*log2(e)
          else if (which == 1)
            Kb[((size_t)bh * 2048 + t) * 64 + d] = __float2bfloat16(v);
          else
            Vt[((size_t)bh * 64 + d) * 2048 + t] = __float2bfloat16(v);
        }
      } else {
#pragma unroll
        for (int j = 0; j < 4; ++j) {
          const int row = row0 + j;
          Of[(size_t)row * 1024 + col] = acc[m][n][j] + bv_;
        }
      }
    }
  }
}

// ---------------------------------------------------------------- flash attention
// Swapped QK^T, in-register softmax, LDS-staged K/V tiles (double-buffered,
// counted vmcnt, XOR-swizzled via pre-swizzled global source).
// Q[bh,t,d] (pre-scaled), K[bh,t,d], Vt[bh,d,t]; ctx[b*2048+t, h*64+d] bf16.
__global__ __launch_bounds__(256)
void attn_kernel(const bf16* __restrict__ Q, const bf16* __restrict__ Kb,
                 const bf16* __restrict__ Vt, bf16* __restrict__ ctx) {
  __shared__ bf16 Kl[2][64 * 64];   // [kv][d], 16B-chunk XOR-swizzled
  __shared__ bf16 Vl[2][64 * 64];   // [d][kv], 16B-chunk XOR-swizzled

  const int tid = threadIdx.x, lane = tid & 63, w = tid >> 6;
  const int lo5 = lane & 31, hi = lane >> 5;

  // XCD-aware decode: 512 blocks; blocks of one bh stay on one XCD.
  const int bid = blockIdx.x;
  const int xcd = bid & 7, idx = bid >> 3;
  const int bh = (xcd << 2) | (idx >> 4);
  const int qt = idx & 15;
  const int q0 = qt * 128 + w * 32;

  const bf16* Qbh = Q + (size_t)bh * 2048 * 64;
  const bf16* Kbh = Kb + (size_t)bh * 2048 * 64;
  const bf16* Vbh = Vt + (size_t)bh * 64 * 2048;

  // Q B-fragments: col = lo5 (q), k = f*16 + hi*8 + e
  bf16x8 qf[4];
#pragma unroll
  for (int f = 0; f < 4; ++f)
    qf[f] = *(const bf16x8*)(Qbh + (size_t)(q0 + lo5) * 64 + f * 16 + hi * 8);

  f32x16 o0 = {}, o1 = {};
  float m2 = -1e30f;
  float lsum = 0.f;

  // Stage one 64-kv tile of K and V into LDS buffer `buf`.
  // Chunk c (16B) of tile: r = c>>3 (row), j = c&7 (16B col slot).
  // LDS linear chunk c holds global slot (j ^ (r&7)) of row r.
  auto stage = [&](int buf, int kv) {
#pragma unroll
    for (int i = 0; i < 2; ++i) {
      const int c = (w * 2 + i) * 64 + lane;
      const int r = c >> 3, j = c & 7;
      const int js = (j ^ (r & 7)) * 8;
      GLD16(Kbh + (size_t)(kv + r) * 64 + js, &Kl[buf][c * 8]);
      GLD16(Vbh + (size_t)r * 2048 + kv + js, &Vl[buf][c * 8]);
    }
  };

  stage(0, 0);
  asm volatile("s_waitcnt vmcnt(0)" ::: "memory");
  __builtin_amdgcn_s_barrier();
  __builtin_amdgcn_sched_barrier(0);

  for (int t = 0; t < 32; ++t) {
    const int cur = t & 1;
    const int kv = t << 6;
    if (t < 31) {
      stage(cur ^ 1, kv + 64);
      asm volatile("s_waitcnt vmcnt(4)" ::: "memory");   // my tile-t loads done
    } else {
      asm volatile("s_waitcnt vmcnt(0)" ::: "memory");
    }
    __builtin_amdgcn_s_barrier();          // barrier#1: tile t visible to all
    __builtin_amdgcn_sched_barrier(0);

    // K fragments: row = kt*32+lo5 (kv-local), slot = f*2+hi
    bf16x8 kf[8], vf[8];
#pragma unroll
    for (int kt = 0; kt < 2; ++kt)
#pragma unroll
      for (int f = 0; f < 4; ++f) {
        const int r = kt * 32 + lo5;
        kf[kt * 4 + f] =
            *(const bf16x8*)(&Kl[cur][(r * 8 + (((f << 1) + hi) ^ (r & 7))) * 8]);
      }
    // V fragments: row = dt*32+lo5 (d), slot = ks*2+hi
#pragma unroll
    for (int dt = 0; dt < 2; ++dt)
#pragma unroll
      for (int ks = 0; ks < 4; ++ks) {
        const int r = dt * 32 + lo5;
        vf[dt * 4 + ks] =
            *(const bf16x8*)(&Vl[cur][(r * 8 + (((ks << 1) + hi) ^ (r & 7))) * 8]);
      }
    asm volatile("s_waitcnt lgkmcnt(0)" ::: "memory");
    __builtin_amdgcn_s_barrier();          // barrier#2: all reads of tile t done
    __builtin_amdgcn_sched_barrier(0);

    // QK^T (scores arrive pre-scaled in log2 domain; Q was folded)
    f32x16 s0 = {}, s1 = {};
#pragma unroll
    for (int f = 0; f < 4; ++f) s0 = MFMA32(kf[f], qf[f], s0);
#pragma unroll
    for (int f = 0; f < 4; ++f) s1 = MFMA32(kf[4 + f], qf[f], s1);

    float p[32];
#pragma unroll
    for (int j = 0; j < 16; ++j) { p[j] = s0[j]; p[16 + j] = s1[j]; }
    float pm = p[0];
#pragma unroll
    for (int j = 1; j < 32; ++j) pm = fmaxf(pm, p[j]);
    if (!__all(pm <= m2 + 11.5416f)) {   // defer-max (THR = 8 nats in log2)
      const float mx = fmaxf(pm, __shfl_xor(pm, 32, 64));
      const float mn = fmaxf(m2, mx);
      const float corr = exp2_fast(m2 - mn);
      m2 = mn;
      lsum *= corr;
#pragma unroll
      for (int j = 0; j < 16; ++j) { o0[j] *= corr; o1[j] *= corr; }
    }
    float rs = 0.f;
#pragma unroll
    for (int j = 0; j < 32; ++j) {
      p[j] = exp2_fast(p[j] - m2);
      rs += p[j];
    }
    lsum += rs;

    // P^T B-fragments via cvt_pk + permlane32_swap (in-register redistribute)
    bf16x8 pa[4];
#pragma unroll
    for (int ks = 0; ks < 4; ++ks) {
      const int b0 = ks * 8;
      unsigned int a0 = cvtpk_bf16(p[b0 + 0], p[b0 + 1]);
      unsigned int c0 = cvtpk_bf16(p[b0 + 4], p[b0 + 5]);
      unsigned int a1 = cvtpk_bf16(p[b0 + 2], p[b0 + 3]);
      unsigned int c1 = cvtpk_bf16(p[b0 + 6], p[b0 + 7]);
      permswap(a0, c0, hi);
      permswap(a1, c1, hi);
      u32x4 tt;
      tt.x = a0; tt.y = a1; tt.z = c0; tt.w = c1;
      pa[ks] = __builtin_bit_cast(bf16x8, tt);
    }

    // PV: O^T += V^T * P^T
#pragma unroll
    for (int ks = 0; ks < 4; ++ks) {
      o0 = MFMA32(vf[ks], pa[ks], o0);
      o1 = MFMA32(vf[4 + ks], pa[ks], o1);
    }
  }

  lsum += __shfl_xor(lsum, 32, 64);
  const float inv = 1.f / lsum;
  const int b = bh >> 4, h = bh & 15;
  bf16* crow = ctx + (size_t)(b * 2048 + q0 + lo5) * 1024 + h * 64;
#pragma unroll
  for (int g = 0; g < 4; ++g) {
    uint2 pk0, pk1;
    pk0.x = cvtpk_bf16(o0[4 * g + 0] * inv, o0[4 * g + 1] * inv);
    pk0.y = cvtpk_bf16(o0[4 * g + 2] * inv, o0[4 * g + 3] * inv);
    pk1.x = cvtpk_bf16(o1[4 * g + 0] * inv, o1[4 * g + 1] * inv);
    pk1.y = cvtpk_bf16(o1[4 * g + 2] * inv, o1[4 * g + 3] * inv);
    *(uint2*)(crow + 8 * g + 4 * hi) = pk0;
    *(uint2*)(crow + 32 + 8 * g + 4 * hi) = pk1;
  }
}

// ---------------------------------------------------------------- launch

extern "C" void kernel_launch(void* const* d_in, const int* in_sizes, int n_in,
                              void* d_out, int out_size, void* d_ws, size_t ws_size,
                              hipStream_t stream) {
  const float* x  = (const float*)d_in[0];
  const float* Wq = (const float*)d_in[1];
  const float* bq = (const float*)d_in[2];
  const float* Wk = (const float*)d_in[3];
  const float* bk = (const float*)d_in[4];
  const float* Wv = (const float*)d_in[5];
  const float* bv = (const float*)d_in[6];
  const float* Wo = (const float*)d_in[7];
  const float* bo = (const float*)d_in[8];
  float* out = (float*)d_out;

  char* ws = (char*)d_ws;
  bf16* xb  = (bf16*)(ws);
  bf16* Wt  = (bf16*)(ws + ((size_t)8 << 20));
  bf16* Qb  = (bf16*)(ws + ((size_t)16 << 20));
  bf16* Kb  = (bf16*)(ws + ((size_t)24 << 20));
  bf16* Vt  = (bf16*)(ws + ((size_t)32 << 20));
  bf16* ctx = (bf16*)(ws + ((size_t)40 << 20));
  float* ba = (float*)(ws + ((size_t)48 << 20));

  convert_x<<<dim3(4096), dim3(256), 0, stream>>>(x, xb);
  convert_w<<<dim3(4096), dim3(256), 0, stream>>>(Wq, Wk, Wv, Wo, Wt);
  concat_bias<<<dim3(16), dim3(256), 0, stream>>>(bq, bk, bv, bo, ba);

  gemm_bt<0><<<dim3(24, 32), dim3(256), 0, stream>>>(xb, Wt, ba, Qb, Kb, Vt, nullptr, 1024);

  attn_kernel<<<dim3(512), dim3(256), 0, stream>>>(Qb, Kb, Vt, ctx);

  gemm_bt<1><<<dim3(8, 32), dim3(256), 0, stream>>>(
      ctx, Wt + (size_t)3072 * 1024, ba + 3072, nullptr, nullptr, nullptr, out, 1024);
}